// Round 2
// baseline (22869.501 us; speedup 1.0000x reference)
//
#include <hip/hip_runtime.h>
#include <cstdint>

#define N_NODES 100000
#define N_EDGES 3200000
#define N_GRAPHS 64
#define HDIM 256
#define F_IN 128

// ---------------- degree / normalization ----------------
__global__ void init_deg(float* deg, int n) {
    int i = blockIdx.x * blockDim.x + threadIdx.x;
    if (i < n) deg[i] = 1.0f;  // self-loop
}

__global__ void count_deg(const int* __restrict__ dst, float* deg, int nE) {
    int e = blockIdx.x * blockDim.x + threadIdx.x;
    if (e < nE) atomicAdd(&deg[dst[e]], 1.0f);
}

__global__ void deg_to_dinv(float* deg, int n) {
    int i = blockIdx.x * blockDim.x + threadIdx.x;
    if (i < n) {
        float d = deg[i];
        deg[i] = d > 0.0f ? rsqrtf(d) : 0.0f;
    }
}

// ---------------- dense GEMM: out[n,256] = X[n,K] @ W[K,256] ----------------
template <int K>
__global__ void gemm_rows(const float* __restrict__ X, const float* __restrict__ W,
                          float* __restrict__ out, int n) {
    constexpr int ROWS = 4;
    __shared__ float sx[ROWS * K];
    int row0 = blockIdx.x * ROWS;
    int t = threadIdx.x;  // 256 threads, one output column each
    for (int i = t; i < ROWS * K; i += 256) {
        int r = i / K, k = i % K;
        int gr = row0 + r;
        sx[i] = (gr < n) ? X[(size_t)gr * K + k] : 0.0f;
    }
    __syncthreads();
    float acc[ROWS] = {0.f, 0.f, 0.f, 0.f};
#pragma unroll 4
    for (int k = 0; k < K; k++) {
        float w = W[k * HDIM + t];
#pragma unroll
        for (int r = 0; r < ROWS; r++) acc[r] += sx[r * K + k] * w;
    }
#pragma unroll
    for (int r = 0; r < ROWS; r++) {
        int gr = row0 + r;
        if (gr < n) out[(size_t)gr * HDIM + t] = acc[r];
    }
}

// ---------------- self-loop init: out[i] = h[i] * dinv[node]^2 ----------------
__global__ void self_init(const float* __restrict__ h, const float* __restrict__ dinv,
                          float* __restrict__ out, int n) {
    int idx = blockIdx.x * blockDim.x + threadIdx.x;
    if (idx < n * HDIM) {
        int node = idx >> 8;
        float di = dinv[node];
        out[idx] = h[idx] * di * di;
    }
}

// ---------------- edge scatter: out[dst] += h[src] * dinv[s]*dinv[d] ----------------
__global__ void scatter_edges(const float* __restrict__ h, const int* __restrict__ src,
                              const int* __restrict__ dst, const float* __restrict__ dinv,
                              float* __restrict__ out, int nE) {
    constexpr int CHUNK = 128;
    __shared__ int s_s[CHUNK];
    __shared__ int s_d[CHUNK];
    __shared__ float s_n[CHUNK];
    int e0 = blockIdx.x * CHUNK;
    int t = threadIdx.x;
    for (int i = t; i < CHUNK; i += 256) {
        int e = e0 + i;
        if (e < nE) {
            int s = src[e], d = dst[e];
            s_s[i] = s;
            s_d[i] = d;
            s_n[i] = dinv[s] * dinv[d];
        } else {
            s_s[i] = 0; s_d[i] = 0; s_n[i] = 0.0f;
        }
    }
    __syncthreads();
    int lane = t & 63;
    int sub = t >> 6;  // wave id 0..3
    int nloc = nE - e0;
    if (nloc > CHUNK) nloc = CHUNK;
    for (int i = sub; i < nloc; i += 4) {
        int s = s_s[i], d = s_d[i];
        float norm = s_n[i];
        float4 v = ((const float4*)(h + (size_t)s * HDIM))[lane];
        float* o = out + (size_t)d * HDIM + lane * 4;
        atomicAdd(o + 0, v.x * norm);
        atomicAdd(o + 1, v.y * norm);
        atomicAdd(o + 2, v.z * norm);
        atomicAdd(o + 3, v.w * norm);
    }
}

// ---------------- bias + relu in place ----------------
__global__ void bias_relu(float* __restrict__ out, const float* __restrict__ b, int n) {
    int idx = blockIdx.x * blockDim.x + threadIdx.x;
    if (idx < n * HDIM) {
        float v = out[idx] + b[idx & 255];
        out[idx] = v > 0.0f ? v : 0.0f;
    }
}

// ---------------- pooling ----------------
__global__ void zero_kernel(float* p, int n) {
    int i = blockIdx.x * blockDim.x + threadIdx.x;
    if (i < n) p[i] = 0.0f;
}

__global__ void pool_sum(const float* __restrict__ h, const int* __restrict__ batch,
                         float* __restrict__ pool, float* __restrict__ cnt, int n) {
    int idx = blockIdx.x * blockDim.x + threadIdx.x;
    if (idx < n * HDIM) {
        int node = idx >> 8;
        int g = batch[node];
        atomicAdd(&pool[g * HDIM + (idx & 255)], h[idx]);
        if ((idx & 255) == 0) atomicAdd(&cnt[g], 1.0f);
    }
}

__global__ void final_head(const float* __restrict__ pool, const float* __restrict__ cnt,
                           const float* __restrict__ fcw, const float* __restrict__ fcb,
                           float* __restrict__ out) {
    int g = threadIdx.x;
    if (g < N_GRAPHS) {
        float c = cnt[g];
        c = c > 1.0f ? c : 1.0f;
        float inv = 1.0f / c;
        float l0 = fcb[0], l1 = fcb[1];
        for (int f = 0; f < HDIM; f++) {
            float p = pool[g * HDIM + f] * inv;
            l0 += p * fcw[f * 2 + 0];
            l1 += p * fcw[f * 2 + 1];
        }
        float m = fmaxf(l0, l1);
        float lse = m + logf(expf(l0 - m) + expf(l1 - m));
        out[g * 2 + 0] = l0 - lse;
        out[g * 2 + 1] = l1 - lse;
    }
}

extern "C" void kernel_launch(void* const* d_in, const int* in_sizes, int n_in,
                              void* d_out, int out_size, void* d_ws, size_t ws_size,
                              hipStream_t stream) {
    const float* x = (const float*)d_in[0];
    const int* ei = (const int*)d_in[1];      // int inputs are delivered as int32
    const int* batch = (const int*)d_in[2];
    const float* W1 = (const float*)d_in[3];
    const float* b1 = (const float*)d_in[4];
    const float* W2 = (const float*)d_in[5];
    const float* b2 = (const float*)d_in[6];
    const float* fcw = (const float*)d_in[7];
    const float* fcb = (const float*)d_in[8];
    float* out = (float*)d_out;

    const int* src = ei;
    const int* dst = ei + N_EDGES;

    float* ws = (float*)d_ws;
    float* dinv = ws;                                    // N (holds deg then dinv)
    float* A = ws + ((N_NODES + 255) & ~255);            // N*256
    float* B = A + (size_t)N_NODES * HDIM;               // N*256
    float* pool = B + (size_t)N_NODES * HDIM;            // 64*256
    float* cnt = pool + N_GRAPHS * HDIM;                 // 64

    int nElem = N_NODES * HDIM;

    // normalization
    init_deg<<<(N_NODES + 255) / 256, 256, 0, stream>>>(dinv, N_NODES);
    count_deg<<<(N_EDGES + 255) / 256, 256, 0, stream>>>(dst, dinv, N_EDGES);
    deg_to_dinv<<<(N_NODES + 255) / 256, 256, 0, stream>>>(dinv, N_NODES);

    // ---- layer 1 ----
    gemm_rows<F_IN><<<(N_NODES + 3) / 4, 256, 0, stream>>>(x, W1, A, N_NODES);
    self_init<<<(nElem + 255) / 256, 256, 0, stream>>>(A, dinv, B, N_NODES);
    scatter_edges<<<(N_EDGES + 127) / 128, 256, 0, stream>>>(A, src, dst, dinv, B, N_EDGES);
    bias_relu<<<(nElem + 255) / 256, 256, 0, stream>>>(B, b1, N_NODES);

    // ---- layer 2 ----
    gemm_rows<HDIM><<<(N_NODES + 3) / 4, 256, 0, stream>>>(B, W2, A, N_NODES);
    self_init<<<(nElem + 255) / 256, 256, 0, stream>>>(A, dinv, B, N_NODES);
    scatter_edges<<<(N_EDGES + 127) / 128, 256, 0, stream>>>(A, src, dst, dinv, B, N_EDGES);
    bias_relu<<<(nElem + 255) / 256, 256, 0, stream>>>(B, b2, N_NODES);

    // ---- pool + head ----
    zero_kernel<<<(N_GRAPHS * HDIM + N_GRAPHS + 255) / 256, 256, 0, stream>>>(
        pool, N_GRAPHS * HDIM + N_GRAPHS);
    pool_sum<<<(nElem + 255) / 256, 256, 0, stream>>>(B, batch, pool, cnt, N_NODES);
    final_head<<<1, 64, 0, stream>>>(pool, cnt, fcw, fcb, out);
}

// Round 3
// 1902.736 us; speedup vs baseline: 12.0193x; 12.0193x over previous
//
#include <hip/hip_runtime.h>
#include <cstdint>

#define N_NODES 100000
#define N_EDGES 3200000
#define N_GRAPHS 64
#define HDIM 256
#define F_IN 128

// ---------------- utility ----------------
__global__ void zero_int(int* p, int n) {
    int i = blockIdx.x * blockDim.x + threadIdx.x;
    if (i < n) p[i] = 0;
}
__global__ void zero_f(float* p, int n) {
    int i = blockIdx.x * blockDim.x + threadIdx.x;
    if (i < n) p[i] = 0.0f;
}

// ---------------- CSR build ----------------
__global__ void histogram_dst(const int* __restrict__ dst, int* __restrict__ counts, int nE) {
    int e = blockIdx.x * blockDim.x + threadIdx.x;
    if (e < nE) atomicAdd(&counts[dst[e]], 1);
}

// dinv[i] = rsqrt(indeg + 1)   (self-loop; always > 0)
__global__ void make_dinv(const int* __restrict__ counts, float* __restrict__ dinv, int n) {
    int i = blockIdx.x * blockDim.x + threadIdx.x;
    if (i < n) dinv[i] = rsqrtf((float)counts[i] + 1.0f);
}

// in-place exclusive scan over n ints, single block of 1024 threads
__global__ void scan_exclusive(int* __restrict__ data, int n) {
    __shared__ int lds[1024];
    __shared__ int carry_s;
    int t = threadIdx.x;
    if (t == 0) carry_s = 0;
    __syncthreads();
    for (int base = 0; base < n; base += 1024) {
        int i = base + t;
        int v = (i < n) ? data[i] : 0;
        lds[t] = v;
        __syncthreads();
        for (int off = 1; off < 1024; off <<= 1) {
            int add = (t >= off) ? lds[t - off] : 0;
            __syncthreads();
            lds[t] += add;
            __syncthreads();
        }
        int excl = carry_s + lds[t] - v;
        if (i < n) data[i] = excl;
        int total = lds[1023];
        __syncthreads();  // everyone has read carry_s before update
        if (t == 0) carry_s += total;
        __syncthreads();
    }
}

// cursor trick: ptr[d] starts at start(d); after fill ptr[d] == end(d).
// reader: begin(d) = d ? ptr[d-1] : 0 ; end(d) = ptr[d]
__global__ void csr_fill(const int* __restrict__ src, const int* __restrict__ dst,
                         int* __restrict__ ptr, int* __restrict__ csr_src, int nE) {
    int e = blockIdx.x * blockDim.x + threadIdx.x;
    if (e < nE) {
        int pos = atomicAdd(&ptr[dst[e]], 1);
        csr_src[pos] = src[e];
    }
}

// ---------------- aggregation: out[d] = dinv[d] * ( dinv[d]*h[d] + sum_s dinv[s]*h[s] )
// one wave per node; F=256 -> float4/lane, F=128 -> float2/lane
__global__ void csr_agg256(const float* __restrict__ h, const int* __restrict__ ptr,
                           const int* __restrict__ csr_src, const float* __restrict__ dinv,
                           float* __restrict__ out, int n) {
    int wave = threadIdx.x >> 6;
    int lane = threadIdx.x & 63;
    int node = blockIdx.x * 4 + wave;
    if (node >= n) return;
    int begin = node ? ptr[node - 1] : 0;
    int end = ptr[node];
    float dn = dinv[node];
    float4 v = ((const float4*)(h + (size_t)node * 256))[lane];
    float4 acc;
    acc.x = dn * v.x; acc.y = dn * v.y; acc.z = dn * v.z; acc.w = dn * v.w;
    for (int i = begin; i < end; i++) {
        int s = csr_src[i];
        float ds = dinv[s];
        float4 hv = ((const float4*)(h + (size_t)s * 256))[lane];
        acc.x += ds * hv.x; acc.y += ds * hv.y; acc.z += ds * hv.z; acc.w += ds * hv.w;
    }
    acc.x *= dn; acc.y *= dn; acc.z *= dn; acc.w *= dn;
    ((float4*)(out + (size_t)node * 256))[lane] = acc;
}

__global__ void csr_agg128(const float* __restrict__ h, const int* __restrict__ ptr,
                           const int* __restrict__ csr_src, const float* __restrict__ dinv,
                           float* __restrict__ out, int n) {
    int wave = threadIdx.x >> 6;
    int lane = threadIdx.x & 63;
    int node = blockIdx.x * 4 + wave;
    if (node >= n) return;
    int begin = node ? ptr[node - 1] : 0;
    int end = ptr[node];
    float dn = dinv[node];
    float2 v = ((const float2*)(h + (size_t)node * 128))[lane];
    float2 acc;
    acc.x = dn * v.x; acc.y = dn * v.y;
    for (int i = begin; i < end; i++) {
        int s = csr_src[i];
        float ds = dinv[s];
        float2 hv = ((const float2*)(h + (size_t)s * 128))[lane];
        acc.x += ds * hv.x; acc.y += ds * hv.y;
    }
    acc.x *= dn; acc.y *= dn;
    ((float2*)(out + (size_t)node * 128))[lane] = acc;
}

// ---------------- GEMM + bias + relu: out[n,256] = relu(X[n,K] @ W[K,256] + b)
// ROWS=8; n % 8 == 0 (100000 = 8*12500)
template <int K>
__global__ void gemm_bias_relu(const float* __restrict__ X, const float* __restrict__ W,
                               const float* __restrict__ b, float* __restrict__ out, int n) {
    constexpr int ROWS = 8;
    __shared__ float sx[ROWS * K];
    int row0 = blockIdx.x * ROWS;
    int t = threadIdx.x;  // 256 threads, one output column each
    // 8 rows are contiguous in X: load ROWS*K floats as float4
    {
        const float4* xs = (const float4*)(X + (size_t)row0 * K);
        float4* ss = (float4*)sx;
        constexpr int NV = ROWS * K / 4;
        for (int i = t; i < NV; i += 256) ss[i] = xs[i];
    }
    __syncthreads();
    float acc[ROWS];
#pragma unroll
    for (int r = 0; r < ROWS; r++) acc[r] = 0.0f;
#pragma unroll 4
    for (int k = 0; k < K; k++) {
        float w = W[k * HDIM + t];
#pragma unroll
        for (int r = 0; r < ROWS; r++) acc[r] += sx[r * K + k] * w;
    }
    float bias = b[t];
#pragma unroll
    for (int r = 0; r < ROWS; r++) {
        float v = acc[r] + bias;
        out[(size_t)(row0 + r) * HDIM + t] = v > 0.0f ? v : 0.0f;
    }
}

// ---------------- pooling: batch is sorted by graph id -> run-length accumulate
__global__ void pool_sum_runs(const float* __restrict__ h, const int* __restrict__ batch,
                              float* __restrict__ pool, float* __restrict__ cnt, int n) {
    constexpr int ROWS = 128;
    int f = threadIdx.x;  // 256 threads = feature id
    int r0 = blockIdx.x * ROWS;
    int rend = r0 + ROWS;
    if (rend > n) rend = n;
    float acc = 0.0f;
    int cur = batch[r0];
    int runlen = 0;
    for (int r = r0; r < rend; r++) {
        int g = batch[r];  // broadcast load
        if (g != cur) {
            atomicAdd(&pool[cur * HDIM + f], acc);
            if (f == 0) atomicAdd(&cnt[cur], (float)runlen);
            acc = 0.0f; runlen = 0; cur = g;
        }
        acc += h[(size_t)r * HDIM + f];
        runlen++;
    }
    atomicAdd(&pool[cur * HDIM + f], acc);
    if (f == 0) atomicAdd(&cnt[cur], (float)runlen);
}

__global__ void final_head(const float* __restrict__ pool, const float* __restrict__ cnt,
                           const float* __restrict__ fcw, const float* __restrict__ fcb,
                           float* __restrict__ out) {
    int g = threadIdx.x;
    if (g < N_GRAPHS) {
        float c = cnt[g];
        c = c > 1.0f ? c : 1.0f;
        float inv = 1.0f / c;
        float l0 = fcb[0], l1 = fcb[1];
        for (int f = 0; f < HDIM; f++) {
            float p = pool[g * HDIM + f] * inv;
            l0 += p * fcw[f * 2 + 0];
            l1 += p * fcw[f * 2 + 1];
        }
        float m = fmaxf(l0, l1);
        float lse = m + logf(expf(l0 - m) + expf(l1 - m));
        out[g * 2 + 0] = l0 - lse;
        out[g * 2 + 1] = l1 - lse;
    }
}

extern "C" void kernel_launch(void* const* d_in, const int* in_sizes, int n_in,
                              void* d_out, int out_size, void* d_ws, size_t ws_size,
                              hipStream_t stream) {
    const float* x = (const float*)d_in[0];
    const int* ei = (const int*)d_in[1];  // int inputs delivered as int32
    const int* batch = (const int*)d_in[2];
    const float* W1 = (const float*)d_in[3];
    const float* b1 = (const float*)d_in[4];
    const float* W2 = (const float*)d_in[5];
    const float* b2 = (const float*)d_in[6];
    const float* fcw = (const float*)d_in[7];
    const float* fcb = (const float*)d_in[8];
    float* out = (float*)d_out;

    const int* src = ei;
    const int* dst = ei + N_EDGES;

    // workspace layout
    char* ws = (char*)d_ws;
    float* dinv = (float*)ws;                 ws += sizeof(float) * ((N_NODES + 255) & ~255);
    int* ptr = (int*)ws;                      ws += sizeof(int) * ((N_NODES + 255) & ~255);
    int* csr_src = (int*)ws;                  ws += sizeof(int) * (size_t)N_EDGES;
    float* A = (float*)ws;                    ws += sizeof(float) * (size_t)N_NODES * HDIM;
    float* B = (float*)ws;                    ws += sizeof(float) * (size_t)N_NODES * HDIM;
    float* pool = (float*)ws;                 ws += sizeof(float) * N_GRAPHS * HDIM;
    float* cnt = (float*)ws;

    // ---- CSR build (per call; ws is re-poisoned) ----
    zero_int<<<(N_NODES + 255) / 256, 256, 0, stream>>>(ptr, N_NODES);
    histogram_dst<<<(N_EDGES + 255) / 256, 256, 0, stream>>>(dst, ptr, N_EDGES);
    make_dinv<<<(N_NODES + 255) / 256, 256, 0, stream>>>(ptr, dinv, N_NODES);
    scan_exclusive<<<1, 1024, 0, stream>>>(ptr, N_NODES);
    csr_fill<<<(N_EDGES + 255) / 256, 256, 0, stream>>>(src, dst, ptr, csr_src, N_EDGES);

    // ---- layer 1: propagate (128 feats) then transform ----
    csr_agg128<<<(N_NODES + 3) / 4, 256, 0, stream>>>(x, ptr, csr_src, dinv, A, N_NODES);
    gemm_bias_relu<F_IN><<<N_NODES / 8, 256, 0, stream>>>(A, W1, b1, B, N_NODES);

    // ---- layer 2: propagate (256 feats) then transform ----
    csr_agg256<<<(N_NODES + 3) / 4, 256, 0, stream>>>(B, ptr, csr_src, dinv, A, N_NODES);
    gemm_bias_relu<HDIM><<<N_NODES / 8, 256, 0, stream>>>(A, W2, b2, B, N_NODES);

    // ---- pool + head ----
    zero_f<<<(N_GRAPHS * HDIM + N_GRAPHS + 255) / 256, 256, 0, stream>>>(pool,
                                                                         N_GRAPHS * HDIM + N_GRAPHS);
    pool_sum_runs<<<(N_NODES + 127) / 128, 256, 0, stream>>>(B, batch, pool, cnt, N_NODES);
    final_head<<<1, 64, 0, stream>>>(pool, cnt, fcw, fcb, out);
}

// Round 4
// 1472.632 us; speedup vs baseline: 15.5297x; 1.2921x over previous
//
#include <hip/hip_runtime.h>
#include <cstdint>

#define N_NODES 100000
#define N_EDGES 3200000
#define N_GRAPHS 64
#define HDIM 256
#define F_IN 128

typedef __attribute__((ext_vector_type(8))) short bf16x8;
typedef __attribute__((ext_vector_type(4))) float f32x4;

// ---------------- bf16 helpers ----------------
__device__ __forceinline__ unsigned short f2bf(float f) {
    unsigned int b = __float_as_uint(f);
    b = (b + 0x7FFFu + ((b >> 16) & 1u)) >> 16;
    return (unsigned short)b;
}
__device__ __forceinline__ float bf2f_lo(unsigned int u) { return __uint_as_float(u << 16); }
__device__ __forceinline__ float bf2f_hi(unsigned int u) { return __uint_as_float(u & 0xFFFF0000u); }

// ---------------- utility ----------------
__global__ void zero_int(int* p, int n) {
    int i = blockIdx.x * blockDim.x + threadIdx.x;
    if (i < n) p[i] = 0;
}
__global__ void zero_f(float* p, int n) {
    int i = blockIdx.x * blockDim.x + threadIdx.x;
    if (i < n) p[i] = 0.0f;
}

// ---------------- CSR build ----------------
__global__ void histogram_dst(const int* __restrict__ dst, int* __restrict__ counts, int nE) {
    int e = blockIdx.x * blockDim.x + threadIdx.x;
    if (e < nE) atomicAdd(&counts[dst[e]], 1);
}

__global__ void make_dinv(const int* __restrict__ counts, float* __restrict__ dinv, int n) {
    int i = blockIdx.x * blockDim.x + threadIdx.x;
    if (i < n) dinv[i] = rsqrtf((float)counts[i] + 1.0f);
}

__global__ void scan_exclusive(int* __restrict__ data, int n) {
    __shared__ int lds[1024];
    __shared__ int carry_s;
    int t = threadIdx.x;
    if (t == 0) carry_s = 0;
    __syncthreads();
    for (int base = 0; base < n; base += 1024) {
        int i = base + t;
        int v = (i < n) ? data[i] : 0;
        lds[t] = v;
        __syncthreads();
        for (int off = 1; off < 1024; off <<= 1) {
            int add = (t >= off) ? lds[t - off] : 0;
            __syncthreads();
            lds[t] += add;
            __syncthreads();
        }
        int excl = carry_s + lds[t] - v;
        if (i < n) data[i] = excl;
        int total = lds[1023];
        __syncthreads();
        if (t == 0) carry_s += total;
        __syncthreads();
    }
}

__global__ void csr_fill(const int* __restrict__ src, const int* __restrict__ dst,
                         int* __restrict__ ptr, int* __restrict__ csr_src, int nE) {
    int e = blockIdx.x * blockDim.x + threadIdx.x;
    if (e < nE) {
        int pos = atomicAdd(&ptr[dst[e]], 1);
        csr_src[pos] = src[e];
    }
}

// ---------------- x -> bf16 pre-scaled: x_pre[n] = bf16(dinv[n] * x[n]) ----------------
__global__ void convert_x_pre(const float* __restrict__ x, const float* __restrict__ dinv,
                              unsigned short* __restrict__ xp, int n) {
    int tid = blockIdx.x * blockDim.x + threadIdx.x;  // over n*F_IN/4
    if (tid >= n * (F_IN / 4)) return;
    int node = tid / (F_IN / 4);
    float di = dinv[node];
    float4 v = ((const float4*)x)[tid];
    ushort4 o;
    o.x = f2bf(v.x * di); o.y = f2bf(v.y * di); o.z = f2bf(v.z * di); o.w = f2bf(v.w * di);
    ((ushort4*)xp)[tid] = o;
}

// ---------------- pack W[K][256] fp32 -> hi/lo bf16 in MFMA B-fragment order ----------------
// fragment (kt, ct): pos = (kt*16+ct)*512 + (quad*16 + (c&15))*8 + j, quad=(k>>3)&3, j=k&7
__global__ void pack_w(const float* __restrict__ W, unsigned short* __restrict__ hi,
                       unsigned short* __restrict__ lo, int K) {
    int idx = blockIdx.x * blockDim.x + threadIdx.x;
    if (idx >= K * HDIM) return;
    int k = idx >> 8, c = idx & 255;
    float w = W[idx];
    unsigned short h = f2bf(w);
    float hf = __uint_as_float((unsigned int)h << 16);
    unsigned short l = f2bf(w - hf);
    int pos = ((k >> 5) * 16 + (c >> 4)) * 512 + ((((k >> 3) & 3) * 16) + (c & 15)) * 8 + (k & 7);
    hi[pos] = h;
    lo[pos] = l;
}

// ---------------- aggregation (bf16 in, bf16 out) ----------------
// out[d] = bf16( dinv[d] * ( h_pre[d] + sum_s h_pre[s] ) ), h_pre already dinv-scaled
__global__ void csr_agg128_bf16(const unsigned short* __restrict__ h, const int* __restrict__ ptr,
                                const int* __restrict__ csr, const float* __restrict__ dinv,
                                unsigned short* __restrict__ out, int n) {
    int wave = threadIdx.x >> 6, lane = threadIdx.x & 63;
    int node = blockIdx.x * 4 + wave;
    if (node >= n) return;
    int begin = node ? ptr[node - 1] : 0;
    int end = ptr[node];
    unsigned int u = *(const unsigned int*)(h + (size_t)node * 128 + lane * 2);
    float a0 = bf2f_lo(u), a1 = bf2f_hi(u);
    int i = begin;
    for (; i + 1 < end; i += 2) {
        int s0 = csr[i], s1 = csr[i + 1];
        unsigned int u0 = *(const unsigned int*)(h + (size_t)s0 * 128 + lane * 2);
        unsigned int u1 = *(const unsigned int*)(h + (size_t)s1 * 128 + lane * 2);
        a0 += bf2f_lo(u0); a1 += bf2f_hi(u0);
        a0 += bf2f_lo(u1); a1 += bf2f_hi(u1);
    }
    if (i < end) {
        int s = csr[i];
        unsigned int u0 = *(const unsigned int*)(h + (size_t)s * 128 + lane * 2);
        a0 += bf2f_lo(u0); a1 += bf2f_hi(u0);
    }
    float dn = dinv[node];
    unsigned int o = (unsigned int)f2bf(a0 * dn) | ((unsigned int)f2bf(a1 * dn) << 16);
    *(unsigned int*)(out + (size_t)node * 128 + lane * 2) = o;
}

__global__ void csr_agg256_bf16(const unsigned short* __restrict__ h, const int* __restrict__ ptr,
                                const int* __restrict__ csr, const float* __restrict__ dinv,
                                unsigned short* __restrict__ out, int n) {
    int wave = threadIdx.x >> 6, lane = threadIdx.x & 63;
    int node = blockIdx.x * 4 + wave;
    if (node >= n) return;
    int begin = node ? ptr[node - 1] : 0;
    int end = ptr[node];
    uint2 u = *(const uint2*)(h + (size_t)node * 256 + lane * 4);
    float a0 = bf2f_lo(u.x), a1 = bf2f_hi(u.x), a2 = bf2f_lo(u.y), a3 = bf2f_hi(u.y);
    int i = begin;
    for (; i + 1 < end; i += 2) {
        int s0 = csr[i], s1 = csr[i + 1];
        uint2 u0 = *(const uint2*)(h + (size_t)s0 * 256 + lane * 4);
        uint2 u1 = *(const uint2*)(h + (size_t)s1 * 256 + lane * 4);
        a0 += bf2f_lo(u0.x); a1 += bf2f_hi(u0.x); a2 += bf2f_lo(u0.y); a3 += bf2f_hi(u0.y);
        a0 += bf2f_lo(u1.x); a1 += bf2f_hi(u1.x); a2 += bf2f_lo(u1.y); a3 += bf2f_hi(u1.y);
    }
    if (i < end) {
        int s = csr[i];
        uint2 u0 = *(const uint2*)(h + (size_t)s * 256 + lane * 4);
        a0 += bf2f_lo(u0.x); a1 += bf2f_hi(u0.x); a2 += bf2f_lo(u0.y); a3 += bf2f_hi(u0.y);
    }
    float dn = dinv[node];
    uint2 o;
    o.x = (unsigned int)f2bf(a0 * dn) | ((unsigned int)f2bf(a1 * dn) << 16);
    o.y = (unsigned int)f2bf(a2 * dn) | ((unsigned int)f2bf(a3 * dn) << 16);
    *(uint2*)(out + (size_t)node * 256 + lane * 4) = o;
}

// ---------------- MFMA GEMM: out[n,256] = act(A[n,K] @ (Whi+Wlo) + b) ----------------
// block: 256 thr = 4 waves; wave: 32 rows (2 strips of 16) x 256 cols
// PRESCALE: out bf16 = dinv[row]*relu(v);  else: out fp32 = relu(v)
template <int K, bool PRESCALE>
__global__ __launch_bounds__(256) void gemm_mfma(
    const unsigned short* __restrict__ A, const unsigned short* __restrict__ Whi,
    const unsigned short* __restrict__ Wlo, const float* __restrict__ bias,
    const float* __restrict__ dinv, void* __restrict__ outp, int n) {
    int wave = threadIdx.x >> 6, lane = threadIdx.x & 63;
    int quad = lane >> 4, l16 = lane & 15;
    int rowbase = blockIdx.x * 128 + wave * 32;

    f32x4 acc[2][16];
#pragma unroll
    for (int s = 0; s < 2; s++)
#pragma unroll
        for (int ct = 0; ct < 16; ct++) acc[s][ct] = (f32x4){0.f, 0.f, 0.f, 0.f};

    int r0 = rowbase + l16;
    int r1 = rowbase + 16 + l16;
    int rc0 = r0 < n ? r0 : n - 1;
    int rc1 = r1 < n ? r1 : n - 1;

    for (int kt = 0; kt < K / 32; kt++) {
        bf16x8 a0 = *(const bf16x8*)(A + (size_t)rc0 * K + kt * 32 + quad * 8);
        bf16x8 a1 = *(const bf16x8*)(A + (size_t)rc1 * K + kt * 32 + quad * 8);
        const unsigned short* wh = Whi + (size_t)kt * 16 * 512;
        const unsigned short* wl = Wlo + (size_t)kt * 16 * 512;
#pragma unroll
        for (int ct = 0; ct < 16; ct++) {
            bf16x8 bh = *(const bf16x8*)(wh + ct * 512 + lane * 8);
            bf16x8 bl = *(const bf16x8*)(wl + ct * 512 + lane * 8);
            acc[0][ct] = __builtin_amdgcn_mfma_f32_16x16x32_bf16(a0, bh, acc[0][ct], 0, 0, 0);
            acc[0][ct] = __builtin_amdgcn_mfma_f32_16x16x32_bf16(a0, bl, acc[0][ct], 0, 0, 0);
            acc[1][ct] = __builtin_amdgcn_mfma_f32_16x16x32_bf16(a1, bh, acc[1][ct], 0, 0, 0);
            acc[1][ct] = __builtin_amdgcn_mfma_f32_16x16x32_bf16(a1, bl, acc[1][ct], 0, 0, 0);
        }
    }

#pragma unroll
    for (int s = 0; s < 2; s++) {
#pragma unroll
        for (int ct = 0; ct < 16; ct++) {
            int col = ct * 16 + l16;
            float b = bias[col];
#pragma unroll
            for (int r = 0; r < 4; r++) {
                int row = rowbase + s * 16 + quad * 4 + r;
                if (row < n) {
                    float v = acc[s][ct][r] + b;
                    v = v > 0.0f ? v : 0.0f;
                    if (PRESCALE) {
                        ((unsigned short*)outp)[(size_t)row * HDIM + col] = f2bf(v * dinv[row]);
                    } else {
                        ((float*)outp)[(size_t)row * HDIM + col] = v;
                    }
                }
            }
        }
    }
}

// ---------------- pooling (batch sorted -> run-length) ----------------
__global__ void pool_sum_runs(const float* __restrict__ h, const int* __restrict__ batch,
                              float* __restrict__ pool, float* __restrict__ cnt, int n) {
    constexpr int ROWS = 128;
    int f = threadIdx.x;
    int r0 = blockIdx.x * ROWS;
    int rend = r0 + ROWS;
    if (rend > n) rend = n;
    float acc = 0.0f;
    int cur = batch[r0];
    int runlen = 0;
    for (int r = r0; r < rend; r++) {
        int g = batch[r];
        if (g != cur) {
            atomicAdd(&pool[cur * HDIM + f], acc);
            if (f == 0) atomicAdd(&cnt[cur], (float)runlen);
            acc = 0.0f; runlen = 0; cur = g;
        }
        acc += h[(size_t)r * HDIM + f];
        runlen++;
    }
    atomicAdd(&pool[cur * HDIM + f], acc);
    if (f == 0) atomicAdd(&cnt[cur], (float)runlen);
}

__global__ void final_head(const float* __restrict__ pool, const float* __restrict__ cnt,
                           const float* __restrict__ fcw, const float* __restrict__ fcb,
                           float* __restrict__ out) {
    int g = threadIdx.x;
    if (g < N_GRAPHS) {
        float c = cnt[g];
        c = c > 1.0f ? c : 1.0f;
        float inv = 1.0f / c;
        float l0 = fcb[0], l1 = fcb[1];
        for (int f = 0; f < HDIM; f++) {
            float p = pool[g * HDIM + f] * inv;
            l0 += p * fcw[f * 2 + 0];
            l1 += p * fcw[f * 2 + 1];
        }
        float m = fmaxf(l0, l1);
        float lse = m + logf(expf(l0 - m) + expf(l1 - m));
        out[g * 2 + 0] = l0 - lse;
        out[g * 2 + 1] = l1 - lse;
    }
}

extern "C" void kernel_launch(void* const* d_in, const int* in_sizes, int n_in,
                              void* d_out, int out_size, void* d_ws, size_t ws_size,
                              hipStream_t stream) {
    const float* x = (const float*)d_in[0];
    const int* ei = (const int*)d_in[1];
    const int* batch = (const int*)d_in[2];
    const float* W1 = (const float*)d_in[3];
    const float* b1 = (const float*)d_in[4];
    const float* W2 = (const float*)d_in[5];
    const float* b2 = (const float*)d_in[6];
    const float* fcw = (const float*)d_in[7];
    const float* fcb = (const float*)d_in[8];
    float* out = (float*)d_out;

    const int* src = ei;
    const int* dst = ei + N_EDGES;

    // ---- workspace layout (bytes) ----
    char* ws = (char*)d_ws;
    float* dinv = (float*)ws;            ws += 4 * ((N_NODES + 255) & ~255);
    int* ptr = (int*)ws;                 ws += 4 * ((N_NODES + 255) & ~255);
    int* csr_src = (int*)ws;             ws += 4 * (size_t)N_EDGES;
    unsigned short* W1hi = (unsigned short*)ws; ws += 2 * F_IN * HDIM;
    unsigned short* W1lo = (unsigned short*)ws; ws += 2 * F_IN * HDIM;
    unsigned short* W2hi = (unsigned short*)ws; ws += 2 * HDIM * HDIM;
    unsigned short* W2lo = (unsigned short*)ws; ws += 2 * HDIM * HDIM;
    float* pool = (float*)ws;            ws += 4 * N_GRAPHS * HDIM;
    float* cnt = (float*)ws;             ws += 4 * ((N_GRAPHS + 63) & ~63);
    // R0 region: x_pre | A1 | h1_pre, later reused as h2 (fp32, N*256)
    char* R0 = ws;                       ws += 4 * (size_t)N_NODES * HDIM;
    unsigned short* x_pre = (unsigned short*)R0;                         // N*128 bf16
    unsigned short* A1 = (unsigned short*)(R0 + 2 * (size_t)N_NODES * F_IN);   // N*128 bf16
    unsigned short* h1_pre = (unsigned short*)(R0 + 4 * (size_t)N_NODES * F_IN); // N*256 bf16
    float* h2 = (float*)R0;                                              // N*256 fp32
    unsigned short* A2 = (unsigned short*)ws;  // N*256 bf16

    // ---- CSR build + dinv ----
    zero_int<<<(N_NODES + 255) / 256, 256, 0, stream>>>(ptr, N_NODES);
    histogram_dst<<<(N_EDGES + 255) / 256, 256, 0, stream>>>(dst, ptr, N_EDGES);
    make_dinv<<<(N_NODES + 255) / 256, 256, 0, stream>>>(ptr, dinv, N_NODES);
    scan_exclusive<<<1, 1024, 0, stream>>>(ptr, N_NODES);
    csr_fill<<<(N_EDGES + 255) / 256, 256, 0, stream>>>(src, dst, ptr, csr_src, N_EDGES);

    // ---- conversions / weight packing ----
    convert_x_pre<<<(N_NODES * (F_IN / 4) + 255) / 256, 256, 0, stream>>>(x, dinv, x_pre, N_NODES);
    pack_w<<<(F_IN * HDIM + 255) / 256, 256, 0, stream>>>(W1, W1hi, W1lo, F_IN);
    pack_w<<<(HDIM * HDIM + 255) / 256, 256, 0, stream>>>(W2, W2hi, W2lo, HDIM);

    // ---- layer 1 ----
    csr_agg128_bf16<<<(N_NODES + 3) / 4, 256, 0, stream>>>(x_pre, ptr, csr_src, dinv, A1, N_NODES);
    gemm_mfma<F_IN, true><<<(N_NODES + 127) / 128, 256, 0, stream>>>(A1, W1hi, W1lo, b1, dinv,
                                                                     h1_pre, N_NODES);
    // ---- layer 2 ----
    csr_agg256_bf16<<<(N_NODES + 3) / 4, 256, 0, stream>>>(h1_pre, ptr, csr_src, dinv, A2, N_NODES);
    gemm_mfma<HDIM, false><<<(N_NODES + 127) / 128, 256, 0, stream>>>(A2, W2hi, W2lo, b2, dinv,
                                                                      h2, N_NODES);

    // ---- pool + head ----
    zero_f<<<(N_GRAPHS * HDIM + N_GRAPHS + 255) / 256, 256, 0, stream>>>(
        pool, N_GRAPHS * HDIM + N_GRAPHS);
    pool_sum_runs<<<(N_NODES + 127) / 128, 256, 0, stream>>>(h2, batch, pool, cnt, N_NODES);
    final_head<<<1, 64, 0, stream>>>(pool, cnt, fcw, fcb, out);
}